// Round 5
// baseline (316.155 us; speedup 1.0000x reference)
//
#include <hip/hip_runtime.h>

typedef _Float16 half8 __attribute__((ext_vector_type(8)));
typedef _Float16 half4 __attribute__((ext_vector_type(4)));
typedef float f32x4 __attribute__((ext_vector_type(4)));

#define TT 512
#define HH 64
#define MB 8       // 8 batches/block = 2 independent groups of 4 -> in-wave ILP
#define S  80      // state row stride (halfs): 160B rows -> reads/writes <=2-way banks (free)
#define XS 2056    // xbuf per-batch stride (halfs): 512*4 + 8 pad (pad absorbs t=TT prefetch)

__global__ __launch_bounds__(512, 1)
void lstm_v16(const float* __restrict__ x,
              const float* __restrict__ W_ih,
              const float* __restrict__ W_hh,
              const float* __restrict__ b_ih,
              const float* __restrict__ b_hh,
              const float* __restrict__ W_fc,
              const float* __restrict__ b_fc,
              float* __restrict__ out)
{
    __shared__ __align__(16) _Float16 st[2][MB * S];     // 2560 B: h state, dbuf
    __shared__ __align__(16) _Float16 xbuf[MB * XS];     // 32896 B: ALL x, staged once

    const int tid = threadIdx.x;
    const int w   = tid >> 6;      // wave 0..7
    const int l   = tid & 63;
    const int q   = l >> 4;
    const int col = l & 15;
    const int bt  = col & 3;          // batch-in-group (4 replica col-groups per group)
    const int pbit = (col >> 2) & 1;  // which acc (unit sub-index) this lane updates
    const int b0  = blockIdx.x * MB;

    const float kN = -1.4426950408889634f;   // -log2(e)
    const float kP =  2.8853900817779268f;   // +2*log2(e)

    // ---- persistent A fragments: 2 tiles per wave, units 8w+2q+p ----
    // SHARED by both batch groups (same unit mapping).
    // tile p, A-row m=col: gate-row r = 64*(m&3) + 8w + 2*(m>>2) + p
    // => C: lane (q,col) reg j = gate j of unit 8w+2q+p  (batch col&3 of the group)
    // Weights PRESCALED by exp2 constants (f32 mul BEFORE f16 cvt: single rounding).
    half8 aw[2][3];
    #pragma unroll
    for (int p = 0; p < 2; ++p) {
        const int r = 64 * (col & 3) + 8 * w + 2 * (col >> 2) + p;
        const float scale = ((col & 3) == 2) ? kP : kN;   // gate g -> kP, i/f/o -> kN
        #pragma unroll
        for (int c = 0; c < 2; ++c) {
            const float* src = W_hh + r * HH + 32 * c + 8 * q;
            half8 v;
            #pragma unroll
            for (int j = 0; j < 8; ++j) v[j] = (_Float16)(src[j] * scale);
            aw[p][c] = v;
        }
        half8 v = {};
        if (q == 0) {   // k=64..67 -> W_ih, k=68 -> bias (B supplies 1.0 at k=68)
            #pragma unroll
            for (int j = 0; j < 4; ++j) v[j] = (_Float16)(W_ih[r * 4 + j] * scale);
            v[4] = (_Float16)((b_ih[r] + b_hh[r]) * scale);
        }
        aw[p][2] = v;
    }

    // ---- pre-stage ALL x for this block's 8 batches into LDS (f16) ----
    #pragma unroll
    for (int it = 0; it < (MB * TT) / 512; ++it) {
        const int task = tid + it * 512;
        const int b = task >> 9, t = task & 511;
        float4 v = *(const float4*)(x + ((size_t)(b0 + b) * TT + t) * 4);
        half4 hx;
        hx[0] = (_Float16)v.x; hx[1] = (_Float16)v.y;
        hx[2] = (_Float16)v.z; hx[3] = (_Float16)v.w;
        *(half4*)&xbuf[b * XS + t * 4] = hx;
    }

    // ---- zero h state (both buffers) ----
    for (int i = tid; i < 2 * MB * S; i += 512) (&st[0][0])[i] = (_Float16)0.f;
    __syncthreads();

    // group A: batches bt (st rows 0..3); group B: batches 4+bt (st rows 4..7)
    float csA = 0.f, csB = 0.f;           // cell state: unit 8w+2q+pbit
    const int wrowA = bt * S + 8 * w + 2 * q + pbit;
    const int wrowB = (4 + bt) * S + 8 * w + 2 * q + pbit;
    const bool writer = (col < 8);        // cols 8..15 are replicas
    const _Float16 hone = (_Float16)1.0f, hzer = (_Float16)0.f;
    const f32x4 z4 = {0.f, 0.f, 0.f, 0.f};

    // prologue: x/bias MFMAs for t=0, both groups
    f32x4 axA0, axA1, axB0, axB1;
    {
        half4 xa = *(const half4*)&xbuf[bt * XS + 0];
        half4 xb = *(const half4*)&xbuf[(4 + bt) * XS + 0];
        half8 bxA = {xa[0], xa[1], xa[2], xa[3], hone, hzer, hzer, hzer};
        half8 bxB = {xb[0], xb[1], xb[2], xb[3], hone, hzer, hzer, hzer};
        axA0 = __builtin_amdgcn_mfma_f32_16x16x32_f16(aw[0][2], bxA, z4, 0, 0, 0);
        axA1 = __builtin_amdgcn_mfma_f32_16x16x32_f16(aw[1][2], bxA, z4, 0, 0, 0);
        axB0 = __builtin_amdgcn_mfma_f32_16x16x32_f16(aw[0][2], bxB, z4, 0, 0, 0);
        axB1 = __builtin_amdgcn_mfma_f32_16x16x32_f16(aw[1][2], bxB, z4, 0, 0, 0);
    }

    #pragma unroll 2
    for (int t = 0; t < TT; ++t) {
        const int rb = t & 1, wb = rb ^ 1;
        const _Float16* sr = &st[rb][0];

        // ---- issue ALL loads up front (independent) ----
        half8 hA0 = *(const half8*)&sr[bt * S +      8 * q];          // A: k 0..31
        half8 hA1 = *(const half8*)&sr[bt * S + 32 + 8 * q];          // A: k 32..63
        half8 hB0 = *(const half8*)&sr[(4 + bt) * S +      8 * q];    // B: k 0..31
        half8 hB1 = *(const half8*)&sr[(4 + bt) * S + 32 + 8 * q];    // B: k 32..63
        half4 xa2 = *(const half4*)&xbuf[bt * XS + (t + 1) * 4];      // prefetch (pad-safe)
        half4 xb2 = *(const half4*)&xbuf[(4 + bt) * XS + (t + 1) * 4];

        // ---- h-MFMAs, both groups (independent chains, depth 2 each) ----
        f32x4 aA0 = __builtin_amdgcn_mfma_f32_16x16x32_f16(aw[0][0], hA0, axA0, 0, 0, 0);
        f32x4 aA1 = __builtin_amdgcn_mfma_f32_16x16x32_f16(aw[1][0], hA0, axA1, 0, 0, 0);
        f32x4 aB0 = __builtin_amdgcn_mfma_f32_16x16x32_f16(aw[0][0], hB0, axB0, 0, 0, 0);
        f32x4 aB1 = __builtin_amdgcn_mfma_f32_16x16x32_f16(aw[1][0], hB0, axB1, 0, 0, 0);
        aA0 = __builtin_amdgcn_mfma_f32_16x16x32_f16(aw[0][1], hA1, aA0, 0, 0, 0);
        aA1 = __builtin_amdgcn_mfma_f32_16x16x32_f16(aw[1][1], hA1, aA1, 0, 0, 0);
        aB0 = __builtin_amdgcn_mfma_f32_16x16x32_f16(aw[0][1], hB1, aB0, 0, 0, 0);
        aB1 = __builtin_amdgcn_mfma_f32_16x16x32_f16(aw[1][1], hB1, aB1, 0, 0, 0);

        // ---- x/bias MFMAs for t+1, independent of this step's h ----
        {
            half8 bxA2 = {xa2[0], xa2[1], xa2[2], xa2[3], hone, hzer, hzer, hzer};
            half8 bxB2 = {xb2[0], xb2[1], xb2[2], xb2[3], hone, hzer, hzer, hzer};
            axA0 = __builtin_amdgcn_mfma_f32_16x16x32_f16(aw[0][2], bxA2, z4, 0, 0, 0);
            axA1 = __builtin_amdgcn_mfma_f32_16x16x32_f16(aw[1][2], bxA2, z4, 0, 0, 0);
            axB0 = __builtin_amdgcn_mfma_f32_16x16x32_f16(aw[0][2], bxB2, z4, 0, 0, 0);
            axB1 = __builtin_amdgcn_mfma_f32_16x16x32_f16(aw[1][2], bxB2, z4, 0, 0, 0);
        }

        // ---- update A (independent of update B: scheduler interleaves the chains) ----
        {
            const float gi = pbit ? aA1[0] : aA0[0];   // prescaled by kN
            const float gf = pbit ? aA1[1] : aA0[1];   // prescaled by kN
            const float gg = pbit ? aA1[2] : aA0[2];   // prescaled by kP
            const float go = pbit ? aA1[3] : aA0[3];   // prescaled by kN
            const float EI = __builtin_amdgcn_exp2f(gi);
            const float EF = __builtin_amdgcn_exp2f(gf);
            const float EG = __builtin_amdgcn_exp2f(gg);
            const float rF = __builtin_amdgcn_rcpf(1.f + EF);
            const float r1 = __builtin_amdgcn_rcpf((1.f + EI) * (EG + 1.f));
            csA = csA * rF + (EG - 1.f) * r1;
            const float EO = __builtin_amdgcn_exp2f(go);
            const float EC = __builtin_amdgcn_exp2f(kP * csA);
            const float r2 = __builtin_amdgcn_rcpf((1.f + EO) * (EC + 1.f));
            const float hn = (EC - 1.f) * r2;
            if (writer) st[wb][wrowA] = (_Float16)hn;
        }
        // ---- update B ----
        {
            const float gi = pbit ? aB1[0] : aB0[0];
            const float gf = pbit ? aB1[1] : aB0[1];
            const float gg = pbit ? aB1[2] : aB0[2];
            const float go = pbit ? aB1[3] : aB0[3];
            const float EI = __builtin_amdgcn_exp2f(gi);
            const float EF = __builtin_amdgcn_exp2f(gf);
            const float EG = __builtin_amdgcn_exp2f(gg);
            const float rF = __builtin_amdgcn_rcpf(1.f + EF);
            const float r1 = __builtin_amdgcn_rcpf((1.f + EI) * (EG + 1.f));
            csB = csB * rF + (EG - 1.f) * r1;
            const float EO = __builtin_amdgcn_exp2f(go);
            const float EC = __builtin_amdgcn_exp2f(kP * csB);
            const float r2 = __builtin_amdgcn_rcpf((1.f + EO) * (EC + 1.f));
            const float hn = (EC - 1.f) * r2;
            if (writer) st[wb][wrowB] = (_Float16)hn;
        }
        __syncthreads();
    }

    // ---- FC epilogue: final h in st[0] (TT even) ----
    if (tid < MB * 4) {
        const int b = tid >> 2, o = tid & 3;
        float s = b_fc[o];
        const float* wf = W_fc + o * HH;
        #pragma unroll
        for (int k = 0; k < HH; ++k)
            s = fmaf((float)st[0][b * S + k], wf[k], s);
        out[(size_t)(b0 + b) * 4 + o] = s;
    }
}

extern "C" void kernel_launch(void* const* d_in, const int* in_sizes, int n_in,
                              void* d_out, int out_size, void* d_ws, size_t ws_size,
                              hipStream_t stream) {
    const float* x    = (const float*)d_in[0];
    const float* W_ih = (const float*)d_in[1];
    const float* W_hh = (const float*)d_in[2];
    const float* b_ih = (const float*)d_in[3];
    const float* b_hh = (const float*)d_in[4];
    const float* W_fc = (const float*)d_in[5];
    const float* b_fc = (const float*)d_in[6];
    float* out = (float*)d_out;
    lstm_v16<<<2048 / MB, 512, 0, stream>>>(x, W_ih, W_hh, b_ih, b_hh, W_fc, b_fc, out);
}

// Round 6
// 212.650 us; speedup vs baseline: 1.4867x; 1.4867x over previous
//
#include <hip/hip_runtime.h>

typedef _Float16 half8 __attribute__((ext_vector_type(8)));
typedef _Float16 half4 __attribute__((ext_vector_type(4)));
typedef float f32x4 __attribute__((ext_vector_type(4)));

#define TT 512
#define HH 64
#define MB 8      // real batches per block -> 256 blocks; cols 8..15 are broadcast dups
#define S  88     // state row stride (halfs): 44 dwords/row == 12 mod 32 ->
                  //  h-writes bank-bijective (zero conflict), h-reads spread (<=2-way)
#define XS 4112   // xbuf per-batch stride (halfs): 514*8 -> pad absorbs t+2 prefetch

// lane l <- lane l^8 (within each 16-lane row), full-rate VALU DPP, no LDS
__device__ __forceinline__ float xor8(float v) {
    return __builtin_bit_cast(float,
        __builtin_amdgcn_update_dpp(0, __builtin_bit_cast(int, v),
                                    0x128 /* row_ror:8 == xor 8 in 16-rows */,
                                    0xF, 0xF, true));
}

__global__ __launch_bounds__(512, 1)
void lstm_v17(const float* __restrict__ x,
              const float* __restrict__ W_ih,
              const float* __restrict__ W_hh,
              const float* __restrict__ b_ih,
              const float* __restrict__ b_hh,
              const float* __restrict__ W_fc,
              const float* __restrict__ b_fc,
              float* __restrict__ out)
{
    __shared__ __align__(16) _Float16 st[2][8 * S];      // 2816 B: h state, dbuf
    __shared__ __align__(16) _Float16 xbuf[MB * XS];     // 65792 B: pre-packed x B-frags

    const int tid = threadIdx.x;
    const int w   = tid >> 6;      // wave 0..7
    const int l   = tid & 63;
    const int q   = l >> 4;
    const int col = l & 15;
    const int b0  = blockIdx.x * MB;
    const int xcol = col & 7;      // cols 8..15 broadcast a real batch
    const bool lo = (col < 8);

    const float kN = -1.4426950408889634f;   // -log2(e)
    const float kP =  2.8853900817779268f;   // +2*log2(e)

    // ---- persistent A fragments (weights), 2 tiles per wave ----
    // tile p of wave w covers gate-rows r(m) = 64*(m&3) + 8w + 2*(m>>2) + p
    // => lane (q,col) reg j = gate j of unit u = 8w + 2q + p
    // Weights PRESCALED by the sigmoid/tanh exp2 constants (f32 mul BEFORE f16
    // convert: same single rounding as unscaled).
    half8 aw[2][3];
    #pragma unroll
    for (int p = 0; p < 2; ++p) {
        const int r = 64 * (col & 3) + 8 * w + 2 * (col >> 2) + p;
        const float scale = ((col & 3) == 2) ? kP : kN;   // gate g -> kP, i/f/o -> kN
        #pragma unroll
        for (int c = 0; c < 2; ++c) {
            const float* src = W_hh + r * HH + 32 * c + 8 * q;
            half8 v;
            #pragma unroll
            for (int j = 0; j < 8; ++j) v[j] = (_Float16)(src[j] * scale);
            aw[p][c] = v;
        }
        half8 v = {};
        if (q == 0) {   // k=64..67 -> W_ih, k=68 -> bias (B supplies 1.0 at k=68)
            #pragma unroll
            for (int j = 0; j < 4; ++j) v[j] = (_Float16)(W_ih[r * 4 + j] * scale);
            v[4] = (_Float16)((b_ih[r] + b_hh[r]) * scale);
        }
        aw[p][2] = v;
    }

    // ---- pre-stage x as ready-to-use B-frags: {x0,x1,x2,x3,1,0,0,0} per (b,t) ----
    // (only q=0 lanes' k-slots are nonzero in aw[*][2], so the replicated tail is harmless)
    #pragma unroll
    for (int it = 0; it < (MB * TT) / 512; ++it) {
        const int task = tid + it * 512;
        const int b = task >> 9, t = task & 511;
        float4 v = *(const float4*)(x + ((size_t)(b0 + b) * TT + t) * 4);
        half8 hx;
        hx[0] = (_Float16)v.x; hx[1] = (_Float16)v.y;
        hx[2] = (_Float16)v.z; hx[3] = (_Float16)v.w;
        hx[4] = (_Float16)1.0f; hx[5] = (_Float16)0.f;
        hx[6] = (_Float16)0.f;  hx[7] = (_Float16)0.f;
        *(half8*)&xbuf[b * XS + t * 8] = hx;
    }

    // ---- zero h state (both buffers, all 8 rows) ----
    for (int i = tid; i < 2 * 8 * S; i += 512) (&st[0][0])[i] = (_Float16)0.f;
    __syncthreads();

    float cs2 = 0.f;               // carried state = kP * c  (folds the EC multiply)
    const int wrow = xcol * S + 8 * w + 2 * q + (col >> 3);   // loop-invariant write addr
    const f32x4 z4 = {0.f, 0.f, 0.f, 0.f};

    // x-pipeline: accx* = x-contribution for step t (ready); bxn = B-frag for step t+1
    f32x4 accx0, accx1;
    half8 bxn;
    {
        half8 bx0 = *(const half8*)&xbuf[xcol * XS + 0];
        accx0 = __builtin_amdgcn_mfma_f32_16x16x32_f16(aw[0][2], bx0, z4, 0, 0, 0);
        accx1 = __builtin_amdgcn_mfma_f32_16x16x32_f16(aw[1][2], bx0, z4, 0, 0, 0);
        bxn = *(const half8*)&xbuf[xcol * XS + 8];
    }

    #pragma unroll 4
    for (int t = 0; t < TT; ++t) {
        const int rb = t & 1, wb = rb ^ 1;
        const _Float16* sr = &st[rb][0];

        // ---- critical reads first ----
        half8 bh0 = *(const half8*)&sr[xcol * S +      8 * q];   // k 0..31
        half8 bh1 = *(const half8*)&sr[xcol * S + 32 + 8 * q];   // k 32..63

        // ---- x-MFMAs for t+1: operands already in regs -> issue inside read latency ----
        f32x4 axn0 = __builtin_amdgcn_mfma_f32_16x16x32_f16(aw[0][2], bxn, z4, 0, 0, 0);
        f32x4 axn1 = __builtin_amdgcn_mfma_f32_16x16x32_f16(aw[1][2], bxn, z4, 0, 0, 0);

        // prefetch x B-frag for t+2 (pad-safe: XS covers t=513)
        bxn = *(const half8*)&xbuf[xcol * XS + (t + 2) * 8];

        // ---- h-MFMAs: chain depth 2 (x/bias contribution precomputed last iter) ----
        f32x4 a0 = __builtin_amdgcn_mfma_f32_16x16x32_f16(aw[0][0], bh0, accx0, 0, 0, 0);
        f32x4 a1 = __builtin_amdgcn_mfma_f32_16x16x32_f16(aw[1][0], bh0, accx1, 0, 0, 0);
        a0 = __builtin_amdgcn_mfma_f32_16x16x32_f16(aw[0][1], bh1, a0, 0, 0, 0);
        a1 = __builtin_amdgcn_mfma_f32_16x16x32_f16(aw[1][1], bh1, a1, 0, 0, 0);

        // ---- redistribute: every lane does exactly ONE real cell update ----
        const float s0 = xor8(a1[0]);
        const float s1 = xor8(a1[1]);
        const float s2 = xor8(a1[2]);
        const float s3 = xor8(a1[3]);
        const float gi = lo ? a0[0] : s0;   // prescaled by kN
        const float gf = lo ? a0[1] : s1;   // prescaled by kN
        const float gg = lo ? a0[2] : s2;   // prescaled by kP
        const float go = lo ? a0[3] : s3;   // prescaled by kN

        const float EI = __builtin_amdgcn_exp2f(gi);
        const float EF = __builtin_amdgcn_exp2f(gf);
        const float EG = __builtin_amdgcn_exp2f(gg);
        const float rF = __builtin_amdgcn_rcpf(1.f + EF);
        const float r1 = __builtin_amdgcn_rcpf((1.f + EI) * (EG + 1.f));
        const float Y  = (kP * (EG - 1.f)) * r1;      // kP folded off-chain
        cs2 = cs2 * rF + Y;                           // cs2 == kP * c
        const float EO = __builtin_amdgcn_exp2f(go);
        const float EC = __builtin_amdgcn_exp2f(cs2); // no kP*c multiply on this path
        const float r2 = __builtin_amdgcn_rcpf((1.f + EO) * (EC + 1.f));
        const float hn = (EC - 1.f) * r2;

        st[wb][wrow] = (_Float16)hn;    // bank-bijective across the wave: conflict-free
        __syncthreads();

        accx0 = axn0; accx1 = axn1;
    }

    // ---- FC epilogue: final h in st[0] (TT even) ----
    if (tid < MB * 4) {
        const int b = tid >> 2, o = tid & 3;
        float s = b_fc[o];
        const float* wf = W_fc + o * HH;
        #pragma unroll
        for (int k = 0; k < HH; ++k)
            s = fmaf((float)st[0][b * S + k], wf[k], s);
        out[(size_t)(b0 + b) * 4 + o] = s;
    }
}

extern "C" void kernel_launch(void* const* d_in, const int* in_sizes, int n_in,
                              void* d_out, int out_size, void* d_ws, size_t ws_size,
                              hipStream_t stream) {
    const float* x    = (const float*)d_in[0];
    const float* W_ih = (const float*)d_in[1];
    const float* W_hh = (const float*)d_in[2];
    const float* b_ih = (const float*)d_in[3];
    const float* b_hh = (const float*)d_in[4];
    const float* W_fc = (const float*)d_in[5];
    const float* b_fc = (const float*)d_in[6];
    float* out = (float*)d_out;
    lstm_v17<<<2048 / MB, 512, 0, stream>>>(x, W_ih, W_hh, b_ih, b_hh, W_fc, b_fc, out);
}